// Round 4
// baseline (882.579 us; speedup 1.0000x reference)
//
#include <hip/hip_runtime.h>

#define N_NODES 10000
#define N_EDGES 320000
#define NODE_DIM 128
#define EDGE_DIM 16
#define HIDDEN 256
#define N_OUT 8
#define N_GRAPHS 64
#define LOG2E 1.4426950408889634f

typedef float f32x2 __attribute__((ext_vector_type(2)));
typedef float f32x4 __attribute__((ext_vector_type(4)));
typedef short bf16x8 __attribute__((ext_vector_type(8)));

__device__ __forceinline__ unsigned short f2bf(float f) {
  unsigned int u = __float_as_uint(f);
  unsigned int r = (u + 0x7fff + ((u >> 16) & 1)) >> 16;
  return (unsigned short)r;
}

// D = S0*S1 + S2 packed 2xf32
#define PK1(acc, ap, wp) \
  asm("v_pk_fma_f32 %0, %1, %2, %0" : "+v"(acc) : "v"(ap), "v"(wp))

// ---------------- CSR build ----------------
__global__ void hist_kernel(const int* __restrict__ dst, int* __restrict__ counts, int E) {
  int e = blockIdx.x * blockDim.x + threadIdx.x;
  if (e < E) atomicAdd(&counts[dst[e]], 1);
}

__global__ void scan_kernel(const int* __restrict__ counts, int* __restrict__ offs,
                            int* __restrict__ cursor, int n) {
  __shared__ int part[256];
  int t = threadIdx.x;
  const int chunk = (n + 255) / 256;
  int base = t * chunk;
  int s = 0;
  for (int j = 0; j < chunk; ++j) { int i = base + j; if (i < n) s += counts[i]; }
  part[t] = s;
  __syncthreads();
  for (int off = 1; off < 256; off <<= 1) {
    int v = (t >= off) ? part[t - off] : 0;
    __syncthreads();
    part[t] += v;
    __syncthreads();
  }
  int run = (t == 0) ? 0 : part[t - 1];
  for (int j = 0; j < chunk; ++j) {
    int i = base + j;
    if (i < n) { offs[i] = run; cursor[i] = run; run += counts[i]; }
  }
  if (t == 255) offs[n] = run;
}

__global__ void scatter_kernel(const int* __restrict__ ei, const float* __restrict__ eattr,
                               int* __restrict__ cursor, int* __restrict__ csr_src,
                               float* __restrict__ csr_attr, int E) {
  int e = blockIdx.x * blockDim.x + threadIdx.x;
  if (e >= E) return;
  int s = ei[e];
  int d = ei[E + e];
  int slot = atomicAdd(&cursor[d], 1);
  csr_src[slot] = s;
  const float4* in = (const float4*)(eattr + (size_t)e * 16);
  float4* out = (float4*)(csr_attr + (size_t)slot * 16);
  out[0] = in[0]; out[1] = in[1]; out[2] = in[2]; out[3] = in[3];
}

// ---------------- weight / activation bf16 conversion ----------------
// WT[n][k] = (n<256 ? Wl[k][n] : Wr[k][n-256]) as bf16, n in [0,512)
__global__ void cvt_w(const float* __restrict__ Wl, const float* __restrict__ Wr,
                      unsigned short* __restrict__ WT, int K) {
  int idx = blockIdx.x * 256 + threadIdx.x;
  if (idx >= 512 * K) return;
  int n = idx / K, k = idx - n * K;
  float v = (n < 256) ? Wl[(size_t)k * 256 + n] : Wr[(size_t)k * 256 + (n - 256)];
  WT[idx] = f2bf(v);
}

__global__ void cvt_x(const float* __restrict__ X, unsigned short* __restrict__ XB, int total4) {
  int idx = blockIdx.x * 256 + threadIdx.x;
  if (idx >= total4) return;
  float4 v = *(const float4*)(X + (size_t)idx * 4);
  ushort4 o;
  o.x = f2bf(v.x); o.y = f2bf(v.y); o.z = f2bf(v.z); o.w = f2bf(v.w);
  *(ushort4*)(XB + (size_t)idx * 4) = o;
}

// ---------------- MFMA node GEMM: C[M][512] = A[M][K](bf16) @ W[K][512](bf16,WT=col-major) ----------------
__global__ __launch_bounds__(256) void gemm_mfma(
    const unsigned short* __restrict__ A,   // [M][K] bf16 row-major
    const unsigned short* __restrict__ WT,  // [512][K] bf16 (output-col major)
    const float* __restrict__ bl, const float* __restrict__ br,
    float* __restrict__ C, int M, int K) {
  const int t = threadIdx.x;
  const int wv = t >> 6;
  const int l = t & 63;
  const int bm = blockIdx.x * 64;
  const int bn = blockIdx.y * 64;
  const int col = bn + wv * 16 + (l & 15);
  const int kgrp = (l >> 4) * 8;
  f32x4 acc[4];
#pragma unroll
  for (int mt = 0; mt < 4; ++mt) acc[mt] = (f32x4){0.f, 0.f, 0.f, 0.f};

  int arow[4];
#pragma unroll
  for (int mt = 0; mt < 4; ++mt) {
    int r = bm + mt * 16 + (l & 15);
    arow[mt] = (r < M) ? r : M - 1;
  }

  for (int k0 = 0; k0 < K; k0 += 32) {
    bf16x8 bfrag = *(const bf16x8*)(WT + (size_t)col * K + k0 + kgrp);
#pragma unroll
    for (int mt = 0; mt < 4; ++mt) {
      bf16x8 afrag = *(const bf16x8*)(A + (size_t)arow[mt] * K + k0 + kgrp);
      acc[mt] = __builtin_amdgcn_mfma_f32_16x16x32_bf16(afrag, bfrag, acc[mt], 0, 0, 0);
    }
  }
  const float bias = (col < 256) ? bl[col] : br[col - 256];
#pragma unroll
  for (int mt = 0; mt < 4; ++mt) {
#pragma unroll
    for (int j = 0; j < 4; ++j) {
      int row = bm + mt * 16 + (l >> 4) * 4 + j;
      if (row < M) C[(size_t)row * 512 + col] = acc[mt][j] + bias;
    }
  }
}

// ---------------- fused edge scoring + segment softmax + aggregate + BN + act ----------------
// One wave per dst node; 4 edges/iter; packed v_pk_fma_f32 over the EDGE_DIM axis
// (even/odd-d partial sums; init {xr,xl} folds both adds). Epilogue also writes bf16.
__device__ __forceinline__ void pkstep(f32x2& a0, f32x2& a1, f32x2& a2, f32x2& a3,
                                       f32x2 ap, const f32x2* wp) {
  PK1(a0, ap, wp[0]);
  PK1(a1, ap, wp[1]);
  PK1(a2, ap, wp[2]);
  PK1(a3, ap, wp[3]);
}

__device__ __forceinline__ float edge_score(const float* __restrict__ csr_attr, int e,
                                            const f32x2 Wp[8][4], const float4& xr4,
                                            const float4& att4, const float4& xl) {
  const float* ap = csr_attr + (size_t)e * 16;
  asm("" : "+v"(ap));  // force VGPR address -> vector loads (no s->v copy storm)
  const f32x4* av = (const f32x4*)ap;
  f32x4 q0 = av[0], q1 = av[1], q2 = av[2], q3 = av[3];
  f32x2 acc0 = {xr4.x, xl.x}, acc1 = {xr4.y, xl.y};
  f32x2 acc2 = {xr4.z, xl.z}, acc3 = {xr4.w, xl.w};
  f32x2 p;
  p = __builtin_shufflevector(q0, q0, 0, 1); pkstep(acc0, acc1, acc2, acc3, p, Wp[0]);
  p = __builtin_shufflevector(q0, q0, 2, 3); pkstep(acc0, acc1, acc2, acc3, p, Wp[1]);
  p = __builtin_shufflevector(q1, q1, 0, 1); pkstep(acc0, acc1, acc2, acc3, p, Wp[2]);
  p = __builtin_shufflevector(q1, q1, 2, 3); pkstep(acc0, acc1, acc2, acc3, p, Wp[3]);
  p = __builtin_shufflevector(q2, q2, 0, 1); pkstep(acc0, acc1, acc2, acc3, p, Wp[4]);
  p = __builtin_shufflevector(q2, q2, 2, 3); pkstep(acc0, acc1, acc2, acc3, p, Wp[5]);
  p = __builtin_shufflevector(q3, q3, 0, 1); pkstep(acc0, acc1, acc2, acc3, p, Wp[6]);
  p = __builtin_shufflevector(q3, q3, 2, 3); pkstep(acc0, acc1, acc2, acc3, p, Wp[7]);
  float zx = acc0.x + acc0.y; zx = fmaxf(zx, 0.2f * zx);
  float zy = acc1.x + acc1.y; zy = fmaxf(zy, 0.2f * zy);
  float zz = acc2.x + acc2.y; zz = fmaxf(zz, 0.2f * zz);
  float zw = acc3.x + acc3.y; zw = fmaxf(zw, 0.2f * zw);
  float s = att4.x * zx;
  s = fmaf(att4.y, zy, s);
  s = fmaf(att4.z, zz, s);
  s = fmaf(att4.w, zw, s);
  return s;
}

__global__ __launch_bounds__(256, 3) void edge_gat(
    const float* __restrict__ xlr,
    const int* __restrict__ offs, const int* __restrict__ csr_src,
    const float* __restrict__ csr_attr,
    const float* __restrict__ We, const float* __restrict__ att,
    const float* __restrict__ bconv,
    const float* __restrict__ gamma, const float* __restrict__ beta,
    const float* __restrict__ mean, const float* __restrict__ var,
    float* __restrict__ hout, unsigned short* __restrict__ hbf, int relu_last) {
  const int t = threadIdx.x;
  const int w = t >> 6;
  const int l = t & 63;
  const int h4 = l << 2;
  const int iu = __builtin_amdgcn_readfirstlane(blockIdx.x * 4 + w);

  // packed We pairs over d: Wp[dp][c] = {We[2dp][h4+c], We[2dp+1][h4+c]}
  f32x2 Wp[8][4];
#pragma unroll
  for (int dp = 0; dp < 8; ++dp) {
    float4 r0 = *(const float4*)(We + (2 * dp) * HIDDEN + h4);
    float4 r1 = *(const float4*)(We + (2 * dp + 1) * HIDDEN + h4);
    Wp[dp][0] = (f32x2){r0.x, r1.x};
    Wp[dp][1] = (f32x2){r0.y, r1.y};
    Wp[dp][2] = (f32x2){r0.z, r1.z};
    Wp[dp][3] = (f32x2){r0.w, r1.w};
  }
  float4 att4 = *(const float4*)(att + h4);
  att4.x *= LOG2E; att4.y *= LOG2E; att4.z *= LOG2E; att4.w *= LOG2E;
  const float4 xr4 = *(const float4*)(xlr + (size_t)iu * 512 + HIDDEN + h4);

  const int rs = __builtin_amdgcn_readfirstlane(offs[iu]);
  const int re = __builtin_amdgcn_readfirstlane(offs[iu + 1]);

  float mrun = -1e30f, den = 0.f;
  float4 acc = make_float4(0.f, 0.f, 0.f, 0.f);

  for (int e = rs; e < re; e += 4) {
    const int e0 = e;
    const int e1 = (e + 1 < re) ? e + 1 : e;
    const int e2 = (e + 2 < re) ? e + 2 : e;
    const int e3 = (e + 3 < re) ? e + 3 : e;
    const int s0 = __builtin_amdgcn_readfirstlane(csr_src[e0]);
    const int s1 = __builtin_amdgcn_readfirstlane(csr_src[e1]);
    const int s2 = __builtin_amdgcn_readfirstlane(csr_src[e2]);
    const int s3 = __builtin_amdgcn_readfirstlane(csr_src[e3]);
    const float4 xl0 = *(const float4*)(xlr + (size_t)s0 * 512 + h4);
    const float4 xl1 = *(const float4*)(xlr + (size_t)s1 * 512 + h4);
    const float4 xl2 = *(const float4*)(xlr + (size_t)s2 * 512 + h4);
    const float4 xl3 = *(const float4*)(xlr + (size_t)s3 * 512 + h4);

    float p0 = edge_score(csr_attr, e0, Wp, xr4, att4, xl0);
    float p1 = edge_score(csr_attr, e1, Wp, xr4, att4, xl1);
    float p2 = edge_score(csr_attr, e2, Wp, xr4, att4, xl2);
    float p3 = edge_score(csr_attr, e3, Wp, xr4, att4, xl3);

#pragma unroll
    for (int off = 32; off > 0; off >>= 1) {
      p0 += __shfl_xor(p0, off, 64);
      p1 += __shfl_xor(p1, off, 64);
      p2 += __shfl_xor(p2, off, 64);
      p3 += __shfl_xor(p3, off, 64);
    }
    if (e + 1 >= re) p1 = -1e30f;
    if (e + 2 >= re) p2 = -1e30f;
    if (e + 3 >= re) p3 = -1e30f;

    const float bmx = fmaxf(fmaxf(p0, p1), fmaxf(p2, p3));
    const float nm = fmaxf(mrun, bmx);
    const float sc = exp2f(mrun - nm);
    const float w0 = exp2f(p0 - nm);
    const float w1 = exp2f(p1 - nm);
    const float w2 = exp2f(p2 - nm);
    const float w3 = exp2f(p3 - nm);
    den = fmaf(den, sc, (w0 + w1) + (w2 + w3));
    float tx = w0 * xl0.x; tx = fmaf(w1, xl1.x, tx); tx = fmaf(w2, xl2.x, tx); tx = fmaf(w3, xl3.x, tx);
    float ty = w0 * xl0.y; ty = fmaf(w1, xl1.y, ty); ty = fmaf(w2, xl2.y, ty); ty = fmaf(w3, xl3.y, ty);
    float tz = w0 * xl0.z; tz = fmaf(w1, xl1.z, tz); tz = fmaf(w2, xl2.z, tz); tz = fmaf(w3, xl3.z, tz);
    float tw = w0 * xl0.w; tw = fmaf(w1, xl1.w, tw); tw = fmaf(w2, xl2.w, tw); tw = fmaf(w3, xl3.w, tw);
    acc.x = fmaf(acc.x, sc, tx);
    acc.y = fmaf(acc.y, sc, ty);
    acc.z = fmaf(acc.z, sc, tz);
    acc.w = fmaf(acc.w, sc, tw);
    mrun = nm;
  }

  const float inv = (den > 0.f) ? __frcp_rn(den) : 0.f;
  const float4 bc4 = *(const float4*)(bconv + h4);
  const float4 g4 = *(const float4*)(gamma + h4);
  const float4 b4 = *(const float4*)(beta + h4);
  const float4 m4 = *(const float4*)(mean + h4);
  const float4 v4 = *(const float4*)(var + h4);
  float o[4];
  o[0] = fmaf(acc.x, inv, bc4.x);
  o[1] = fmaf(acc.y, inv, bc4.y);
  o[2] = fmaf(acc.z, inv, bc4.z);
  o[3] = fmaf(acc.w, inv, bc4.w);
  const float gm[4] = {g4.x, g4.y, g4.z, g4.w};
  const float bt[4] = {b4.x, b4.y, b4.z, b4.w};
  const float mn[4] = {m4.x, m4.y, m4.z, m4.w};
  const float vr[4] = {v4.x, v4.y, v4.z, v4.w};
  float4 res;
  float* rp = (float*)&res;
#pragma unroll
  for (int j = 0; j < 4; ++j) {
    float y = (o[j] - mn[j]) * rsqrtf(vr[j] + 1e-5f) * gm[j] + bt[j];
    rp[j] = relu_last ? fmaxf(y, 0.f) : fmaxf(y, 0.01f * y);
  }
  *(float4*)(hout + (size_t)iu * HIDDEN + h4) = res;
  ushort4 rb;
  rb.x = f2bf(rp[0]); rb.y = f2bf(rp[1]); rb.z = f2bf(rp[2]); rb.w = f2bf(rp[3]);
  *(ushort4*)(hbf + (size_t)iu * HIDDEN + h4) = rb;
}

// ---------------- pooling + heads ----------------
__device__ __forceinline__ int lbound(const int* a, int n, int v) {
  int lo = 0, hi = n;
  while (lo < hi) { int m = (lo + hi) >> 1; if (a[m] < v) lo = m + 1; else hi = m; }
  return lo;
}

__global__ void pool_kernel(const float* __restrict__ h, const int* __restrict__ batch,
                            float* __restrict__ g) {
  const int gi = blockIdx.x;
  const int t = threadIdx.x;
  int s = lbound(batch, N_NODES, gi);
  int e = lbound(batch, N_NODES, gi + 1);
  float sum = 0.f;
  for (int i = s; i < e; ++i) sum += h[(size_t)i * HIDDEN + t];
  float c = (float)(e - s);
  g[gi * HIDDEN + t] = sum / fmaxf(c, 1.f);
}

__global__ void head_kernel(const float* __restrict__ g,
                            const float* __restrict__ w1, const float* __restrict__ b1,
                            const float* __restrict__ w2, const float* __restrict__ b2,
                            float* __restrict__ out) {
  int idx = blockIdx.x * 256 + threadIdx.x;
  if (idx >= N_GRAPHS * N_OUT * 2) return;
  int which = idx >> 9;
  int rem = idx & 511;
  int row = rem >> 3, col = rem & 7;
  const float* w = which ? w2 : w1;
  float s = which ? b2[col] : b1[col];
  for (int k = 0; k < HIDDEN; ++k) s = fmaf(g[row * HIDDEN + k], w[k * N_OUT + col], s);
  out[idx] = s;
}

extern "C" void kernel_launch(void* const* d_in, const int* in_sizes, int n_in,
                              void* d_out, int out_size, void* d_ws, size_t ws_size,
                              hipStream_t stream) {
  const float* x     = (const float*)d_in[0];
  const int*   ei    = (const int*)d_in[1];
  const float* eattr = (const float*)d_in[2];
  const int*   batch = (const int*)d_in[3];
  const float* Wl1   = (const float*)d_in[4];
  const float* Wr1   = (const float*)d_in[5];
  const float* We1   = (const float*)d_in[6];
  const float* bl1   = (const float*)d_in[7];
  const float* br1   = (const float*)d_in[8];
  const float* att1  = (const float*)d_in[9];
  const float* b1    = (const float*)d_in[10];
  const float* Wls   = (const float*)d_in[11];
  const float* Wrs   = (const float*)d_in[12];
  const float* Wes   = (const float*)d_in[13];
  const float* bls   = (const float*)d_in[14];
  const float* brs   = (const float*)d_in[15];
  const float* atts  = (const float*)d_in[16];
  const float* bs    = (const float*)d_in[17];
  const float* bng   = (const float*)d_in[18];
  const float* bnb   = (const float*)d_in[19];
  const float* bnm   = (const float*)d_in[20];
  const float* bnv   = (const float*)d_in[21];
  const float* l1w   = (const float*)d_in[22];
  const float* l1b   = (const float*)d_in[23];
  const float* l2w   = (const float*)d_in[24];
  const float* l2b   = (const float*)d_in[25];
  float* out = (float*)d_out;

  char* ws = (char*)d_ws;
  auto alloc = [&](size_t bytes) {
    char* p = ws;
    ws += (bytes + 255) & ~(size_t)255;
    return p;
  };
  int*   counts   = (int*)alloc((size_t)N_NODES * 4);
  int*   offs     = (int*)alloc((size_t)(N_NODES + 1) * 4);
  int*   cursor   = (int*)alloc((size_t)N_NODES * 4);
  int*   csr_src  = (int*)alloc((size_t)N_EDGES * 4);
  float* csr_attr = (float*)alloc((size_t)N_EDGES * 16 * 4);
  float* xlr      = (float*)alloc((size_t)N_NODES * 512 * 4);
  float* hF       = (float*)alloc((size_t)N_NODES * 256 * 4);
  unsigned short* hbf0 = (unsigned short*)alloc((size_t)N_NODES * 256 * 2);
  unsigned short* hbf1 = (unsigned short*)alloc((size_t)N_NODES * 256 * 2);
  unsigned short* xbf  = (unsigned short*)alloc((size_t)N_NODES * NODE_DIM * 2);
  unsigned short* WT   = (unsigned short*)alloc((size_t)512 * 256 * 2);
  float* g        = (float*)alloc((size_t)N_GRAPHS * 256 * 4);

  hipMemsetAsync(counts, 0, (size_t)N_NODES * 4, stream);
  hist_kernel<<<(N_EDGES + 255) / 256, 256, 0, stream>>>(ei + N_EDGES, counts, N_EDGES);
  scan_kernel<<<1, 256, 0, stream>>>(counts, offs, cursor, N_NODES);
  scatter_kernel<<<(N_EDGES + 255) / 256, 256, 0, stream>>>(ei, eattr, cursor, csr_src,
                                                            csr_attr, N_EDGES);
  cvt_x<<<(N_NODES * NODE_DIM / 4 + 255) / 256, 256, 0, stream>>>(x, xbf,
                                                                  N_NODES * NODE_DIM / 4);

  for (int layer = 0; layer < 5; ++layer) {
    int K = (layer == 0) ? NODE_DIM : HIDDEN;
    const float* Wl = (layer == 0) ? Wl1 : Wls + (size_t)(layer - 1) * HIDDEN * HIDDEN;
    const float* Wr = (layer == 0) ? Wr1 : Wrs + (size_t)(layer - 1) * HIDDEN * HIDDEN;
    const float* We = (layer == 0) ? We1 : Wes + (size_t)(layer - 1) * EDGE_DIM * HIDDEN;
    const float* bl = (layer == 0) ? bl1 : bls + (layer - 1) * HIDDEN;
    const float* br = (layer == 0) ? br1 : brs + (layer - 1) * HIDDEN;
    const float* at = (layer == 0) ? att1 : atts + (layer - 1) * HIDDEN;
    const float* bc = (layer == 0) ? b1 : bs + (layer - 1) * HIDDEN;
    const unsigned short* Abf = (layer == 0) ? xbf : ((layer & 1) ? hbf0 : hbf1);
    unsigned short* hbf_out = (layer & 1) ? hbf1 : hbf0;

    cvt_w<<<(512 * K + 255) / 256, 256, 0, stream>>>(Wl, Wr, WT, K);
    dim3 ggrid((N_NODES + 63) / 64, 8);
    gemm_mfma<<<ggrid, 256, 0, stream>>>(Abf, WT, bl, br, xlr, N_NODES, K);
    edge_gat<<<N_NODES / 4, 256, 0, stream>>>(xlr, offs, csr_src, csr_attr, We, at, bc,
                                              bng + layer * HIDDEN, bnb + layer * HIDDEN,
                                              bnm + layer * HIDDEN, bnv + layer * HIDDEN,
                                              hF, hbf_out, (layer == 4) ? 1 : 0);
  }
  pool_kernel<<<N_GRAPHS, 256, 0, stream>>>(hF, batch, g);
  head_kernel<<<4, 256, 0, stream>>>(g, l1w, l1b, l2w, l2b, out);
}